// Round 9
// baseline (287.777 us; speedup 1.0000x reference)
//
#include <hip/hip_runtime.h>

typedef _Float16 f16;
typedef f16 f16x2 __attribute__((ext_vector_type(2)));
typedef f16 f16x4 __attribute__((ext_vector_type(4)));
typedef f16 f16x8 __attribute__((ext_vector_type(8)));
typedef float f32x4 __attribute__((ext_vector_type(4)));

#define NB 4
#define NS 2048
#define ND 1024
#define NH 16
#define NDH 64

__device__ __forceinline__ void gl2lds16(const void* g, void* l) {
  __builtin_amdgcn_global_load_lds(
      (const __attribute__((address_space(1))) unsigned int*)g,
      (__attribute__((address_space(3))) unsigned int*)l, 16, 0, 0);
}

__device__ __forceinline__ float fast_exp2(float x) {
  return __builtin_amdgcn_exp2f(x);  // v_exp_f32
}

__device__ __forceinline__ f16x2 pk_f16(float a, float b) {
  return __builtin_bit_cast(f16x2, __builtin_amdgcn_cvt_pkrtz(a, b));  // v_cvt_pkrtz_f16_f32
}

// ---------------- fp32 -> f16 conversion (all 4 inputs, one launch) ----------
__global__ __launch_bounds__(256) void cvt_all(
    const float* __restrict__ X, const float* __restrict__ Wq,
    const float* __restrict__ Wk, const float* __restrict__ Wv,
    f16* __restrict__ Xh, f16* __restrict__ Wh) {
  int b = blockIdx.x;
  const float* src;
  f16* dst;
  int off;
  if (b < 8192)       { src = X;  dst = Xh;               off = 0; }
  else if (b < 9216)  { src = Wq; dst = Wh;               off = 8192; }
  else if (b < 10240) { src = Wk; dst = Wh + (1u << 20);  off = 9216; }
  else                { src = Wv; dst = Wh + (2u << 20);  off = 10240; }
  int i = (b - off) * 256 + threadIdx.x;
  float4 v = ((const float4*)src)[i];
  f16x4 h = {(f16)v.x, (f16)v.y, (f16)v.z, (f16)v.w};
  ((f16x4*)dst)[i] = h;
}

// ---------------- fused QKV projection GEMM: counted-vmcnt ring ----------
// R7 lesson applied here: the old loop issued 8 gl2lds then IMMEDIATELY
// drained (vmcnt(0) inside __syncthreads) — zero prefetch distance.  New:
// BK=32, 3-buffer LDS ring (48 KB -> 3 blocks/CU), distance-2 prefetch,
// s_waitcnt vmcnt(4) + raw s_barrier (this iter's 4 loads stay in flight;
// each load gets ~2 iterations to land).  Race audit: buf (g+2)%3 written
// at iter g was last read at iter g-1 (barrier-ordered); staging(g)
// completion enforced by vmcnt(4) at barrier(g), one iter before reads at
// g+2.  Tail wrap (&31) stages into never-again-read buffers, no clobber.
// Swizzle for 64 B rows: phys chunk p of row r holds logical p^((r>>1)&3)
// (swizzled GLOBAL source, linear LDS dest — gl2lds rule); reads use
// pc = quad^((lr>>1)&3).  Quarter-wave slot coverage = 2-way (free).
// QF/KF stored in K=32 MFMA fragment order (coalesced 16B/lane in attn):
//   frag f covers dh f*32..f*32+31 of a 16-row tile; lane L holds
//   M[row = tile*16 + (L&15)][dh = f*32 + (L>>4)*8 + j], j=0..7 (16B).
//   Address: (((bh*128+tile)*2+f)*64+L)*8 + j.   Q pre-scaled by 1/8*log2(e).
// VF stored in K=32 PV B-frag order over 32-key groups (kt2 = key>>5):
//   lane (quad,lr), slot j:  key = 32*kt2 + (j<4 ? quad*4+j : 16+quad*4+(j-4)),
//   dh = dt*16+lr.  addr = ((bh*64+kt2)*4+dt)*512 + lane*8 + j.
__global__ __launch_bounds__(256, 3) void qkv_gemm(
    const f16* __restrict__ Xh, const f16* __restrict__ Wh,
    const float* __restrict__ bq, const float* __restrict__ bk,
    const float* __restrict__ bv,
    f16* __restrict__ QF, f16* __restrict__ KF, f16* __restrict__ VF) {
  __shared__ f16 Ah[3][128 * 32];
  __shared__ f16 Bh[3][128 * 32];
  const int t = threadIdx.x;
  const int tileM = blockIdx.x * 128;
  const int nGlob = blockIdx.y * 128;
  const int mat = nGlob >> 10;
  const int col0 = nGlob & 1023;
  const int wave = t >> 6, lane = t & 63;
  const int mOff = (wave & 1) * 64, nOff = (wave >> 1) * 64;
  const int lr = lane & 15, quad = lane >> 4;

  f32x4 acc[4][4];
#pragma unroll
  for (int i = 0; i < 4; i++)
#pragma unroll
    for (int j = 0; j < 4; j++) acc[i][j] = f32x4{0.f, 0.f, 0.f, 0.f};

  // staging: thread t owns rows srow=t>>2 and srow+64, phys chunk t&3;
  // global source chunk = (t&3) ^ ((srow>>1)&3)  (row+64 has same swizzle)
  const int srow = t >> 2;                              // 0..63
  const int sx = ((t & 3) ^ ((srow >> 1) & 3)) * 8;     // f16 offset in row
  const f16* ag = Xh + (size_t)(tileM + srow) * ND + sx;
  const f16* bg = Wh + (size_t)mat * ND * ND + (size_t)(col0 + srow) * ND + sx;
  const bool qk = (mat < 2);
  // read-side: logical chunk quad of row R lives at phys chunk quad^((R>>1)&3);
  // R = mOff|nOff + i*16 + lr -> (R>>1)&3 = (lr>>1)&3
  const int pc = (quad ^ ((lr >> 1) & 3)) * 8;

  // ---- prologue: stage k-iters 0 and 1; wait iter-0 only (vmcnt(4)) ----
  gl2lds16(ag,                          Ah[0] + t * 8);
  gl2lds16(ag + (size_t)64 * ND,        Ah[0] + 2048 + t * 8);
  gl2lds16(bg,                          Bh[0] + t * 8);
  gl2lds16(bg + (size_t)64 * ND,        Bh[0] + 2048 + t * 8);
  gl2lds16(ag + 32,                     Ah[1] + t * 8);
  gl2lds16(ag + (size_t)64 * ND + 32,   Ah[1] + 2048 + t * 8);
  gl2lds16(bg + 32,                     Bh[1] + t * 8);
  gl2lds16(bg + (size_t)64 * ND + 32,   Bh[1] + 2048 + t * 8);
  asm volatile("s_waitcnt vmcnt(4)" ::: "memory");
  __builtin_amdgcn_s_barrier();

  int cur = 0;  // g % 3
  for (int g = 0; g < 32; ++g) {
    // stage iter (g+2)&31 into buf (g+2)%3 (in flight across 2 barriers)
    {
      int s2 = cur + 2; if (s2 >= 3) s2 -= 3;
      const size_t ko = (size_t)(((g + 2) & 31) * 32);
      gl2lds16(ag + ko,                        Ah[s2] + t * 8);
      gl2lds16(ag + (size_t)64 * ND + ko,      Ah[s2] + 2048 + t * 8);
      gl2lds16(bg + ko,                        Bh[s2] + t * 8);
      gl2lds16(bg + (size_t)64 * ND + ko,      Bh[s2] + 2048 + t * 8);
    }
    // fragments (conflict-free via swizzle) + 16 MFMA
    f16x8 af[4], bf[4];
#pragma unroll
    for (int i = 0; i < 4; i++)
      af[i] = *(const f16x8*)(Ah[cur] + (mOff + i * 16 + lr) * 32 + pc);
#pragma unroll
    for (int j = 0; j < 4; j++)
      bf[j] = *(const f16x8*)(Bh[cur] + (nOff + j * 16 + lr) * 32 + pc);
    if (qk) {
#pragma unroll
      for (int i = 0; i < 4; i++)
#pragma unroll
        for (int j = 0; j < 4; j++)
          acc[i][j] = __builtin_amdgcn_mfma_f32_16x16x32_f16(bf[j], af[i], acc[i][j], 0, 0, 0);
    } else {
#pragma unroll
      for (int i = 0; i < 4; i++)
#pragma unroll
        for (int j = 0; j < 4; j++)
          acc[i][j] = __builtin_amdgcn_mfma_f32_16x16x32_f16(af[i], bf[j], acc[i][j], 0, 0, 0);
    }
    // counted barrier: this iter's 4 staging loads stay in flight
    asm volatile("s_waitcnt vmcnt(4)" ::: "memory");
    __builtin_amdgcn_s_barrier();
    cur = (cur == 2) ? 0 : cur + 1;
  }

  if (qk) {
    // acc[i][j][r] = C[dh_n = col0+nOff+j*16+quad*4+r][row = tileM+mOff+i*16+lr]
    const float* bias = (mat == 0) ? bq : bk;
    f16* dst = (mat == 0) ? QF : KF;
    const float sc = (mat == 0) ? 0.18033688f : 1.0f;  // 1/8*log2(e) folded into Q
    const int jstart = (quad & 1) * 4;
#pragma unroll
    for (int j = 0; j < 4; j++) {
      int n0 = col0 + nOff + j * 16;
      int h = n0 >> 6;
      int f = j >> 1;
      int lam = lr + 16 * ((2 * j + (quad >> 1)) & 3);
      float4 bb = *(const float4*)(bias + n0 + quad * 4);
#pragma unroll
      for (int i = 0; i < 4; i++) {
        int sF = tileM + mOff + i * 16;
        int b = sF >> 11, st = (sF & 2047) >> 4;
        int bh = b * NH + h;
        f16x4 v;
#pragma unroll
        for (int r = 0; r < 4; r++) v[r] = (f16)((acc[i][j][r] + (&bb.x)[r]) * sc);
        *(f16x4*)(dst + (((size_t)(bh * 128 + st) * 2 + f) * 64 + lam) * 8 + jstart) = v;
      }
    }
  } else {
    // acc[i][j][r] = C[key = tileM+mOff+i*16+quad*4+r][dh_n = col0+nOff+j*16+lr]
#pragma unroll
    for (int j = 0; j < 4; j++) {
      int n = col0 + nOff + j * 16 + lr;
      int h = n >> 6, dt = (n >> 4) & 3;
      float bb = bv[n];
#pragma unroll
      for (int i = 0; i < 4; i++) {
        int sF = tileM + mOff + i * 16;
        int b = sF >> 11;
        int kt2 = (sF & 2047) >> 5;
        int ts = (sF >> 4) & 1;
        int bh = b * NH + h;
        f16x4 v;
#pragma unroll
        for (int r = 0; r < 4; r++) v[r] = (f16)(acc[i][j][r] + bb);
        *(f16x4*)(VF + ((size_t)(bh * 64 + kt2) * 4 + dt) * 512 +
                  (size_t)(quad * 16 + lr) * 8 + 4 * ts) = v;
      }
    }
  }
}

// ------- flash attention: LDS K/V ring + counted-vmcnt barriers (T4+T5) -----
// (unchanged from R7 — 66 µs, MfmaUtil 51)
__global__ __launch_bounds__(256, 2) void attn_kernel(
    const f16* __restrict__ QF, const f16* __restrict__ KF,
    const f16* __restrict__ VF, float* __restrict__ out) {
  __shared__ f16 LK[3][2048];
  __shared__ f16 LV[3][2048];
  const int t = threadIdx.x, wave = t >> 6, lane = t & 63;
  const int lr = lane & 15, quad = lane >> 4;
  const int bh = blockIdx.x, qb = blockIdx.y;
  const int bb = bh >> 4, hh = bh & 15;
  const size_t bhOff = (size_t)bh * 131072;  // 256 KB of f16 per bh
  const f16* Qp = QF + bhOff + (size_t)lane * 8;
  const f16* Kg = KF + bhOff + (size_t)t * 8;  // staging: thread t -> 16B
  const f16* Vg = VF + bhOff + (size_t)t * 8;
  const int st0 = qb * 16 + wave * 4;  // first of 4 q-tiles for this wave

  // Q B-frags for K=32 (n=q=lane&15, k=dh=(lane>>4)*8+j + f*32), pre-scaled
  f16x8 qf[4][2];
#pragma unroll
  for (int qt = 0; qt < 4; qt++) {
    qf[qt][0] = *(const f16x8*)(Qp + (size_t)(st0 + qt) * 1024);
    qf[qt][1] = *(const f16x8*)(Qp + (size_t)(st0 + qt) * 1024 + 512);
  }

  f32x4 o[4][4];
#pragma unroll
  for (int qt = 0; qt < 4; qt++)
#pragma unroll
    for (int dt = 0; dt < 4; dt++) o[qt][dt] = f32x4{0.f, 0.f, 0.f, 0.f};
  f32x4 lacc[4];
#pragma unroll
  for (int qt = 0; qt < 4; qt++) lacc[qt] = f32x4{0.f, 0.f, 0.f, 0.f};
  const f16x8 ones8 = {(f16)1.f, (f16)1.f, (f16)1.f, (f16)1.f,
                       (f16)1.f, (f16)1.f, (f16)1.f, (f16)1.f};

  // carried pipeline state: P and V of the previous group
  f16x8 pfP[4], vvP[4];

  // ---- prologue: stage groups 0,1; wait group 0 only (vmcnt(2)) ----
  gl2lds16(Kg,        &LK[0][t * 8]);
  gl2lds16(Vg,        &LV[0][t * 8]);
  gl2lds16(Kg + 2048, &LK[1][t * 8]);
  gl2lds16(Vg + 2048, &LV[1][t * 8]);
  asm volatile("s_waitcnt vmcnt(2)" ::: "memory");
  __builtin_amdgcn_s_barrier();

  // ---- peeled g = 0: QK[0] + exp[0]; stage group 2 ----
  {
    f16x8 kk[4];
#pragma unroll
    for (int i = 0; i < 4; i++)
      kk[i] = *(const f16x8*)(&LK[0][i * 512 + lane * 8]);
#pragma unroll
    for (int i = 0; i < 4; i++)
      vvP[i] = *(const f16x8*)(&LV[0][i * 512 + lane * 8]);
    gl2lds16(Kg + 2 * 2048, &LK[2][t * 8]);
    gl2lds16(Vg + 2 * 2048, &LV[2][t * 8]);
    f32x4 sA[4], sB[4];
#pragma unroll
    for (int qt = 0; qt < 4; qt++) {
      sA[qt] = f32x4{0.f, 0.f, 0.f, 0.f};
      sA[qt] = __builtin_amdgcn_mfma_f32_16x16x32_f16(kk[0], qf[qt][0], sA[qt], 0, 0, 0);
      sA[qt] = __builtin_amdgcn_mfma_f32_16x16x32_f16(kk[1], qf[qt][1], sA[qt], 0, 0, 0);
      sB[qt] = f32x4{0.f, 0.f, 0.f, 0.f};
      sB[qt] = __builtin_amdgcn_mfma_f32_16x16x32_f16(kk[2], qf[qt][0], sB[qt], 0, 0, 0);
      sB[qt] = __builtin_amdgcn_mfma_f32_16x16x32_f16(kk[3], qf[qt][1], sB[qt], 0, 0, 0);
    }
#pragma unroll
    for (int qt = 0; qt < 4; qt++) {
      f16x2 a0 = pk_f16(fast_exp2(sA[qt][0]), fast_exp2(sA[qt][1]));
      f16x2 a1 = pk_f16(fast_exp2(sA[qt][2]), fast_exp2(sA[qt][3]));
      f16x2 b0 = pk_f16(fast_exp2(sB[qt][0]), fast_exp2(sB[qt][1]));
      f16x2 b1 = pk_f16(fast_exp2(sB[qt][2]), fast_exp2(sB[qt][3]));
      f16x4 lo = __builtin_shufflevector(a0, a1, 0, 1, 2, 3);
      f16x4 hi = __builtin_shufflevector(b0, b1, 0, 1, 2, 3);
      pfP[qt] = __builtin_shufflevector(lo, hi, 0, 1, 2, 3, 4, 5, 6, 7);
    }
  }
  asm volatile("s_waitcnt vmcnt(2)" ::: "memory");  // group-1 loads landed
  __builtin_amdgcn_s_barrier();

  int cur = 1;  // g % 3
  for (int g = 1; g < 64; ++g) {
    // read group g fragments (linear 16B/lane, conflict-free)
    f16x8 kk[4], vv[4];
#pragma unroll
    for (int i = 0; i < 4; i++)
      kk[i] = *(const f16x8*)(&LK[cur][i * 512 + lane * 8]);
#pragma unroll
    for (int i = 0; i < 4; i++)
      vv[i] = *(const f16x8*)(&LV[cur][i * 512 + lane * 8]);
    // stage group (g+2)&63 into buf (g+2)%3 (wrap staging: harmless, no branch)
    {
      int s2 = cur + 2; if (s2 >= 3) s2 -= 3;
      const size_t nk = (size_t)((g + 2) & 63) * 2048;
      gl2lds16(Kg + nk, &LK[s2][t * 8]);
      gl2lds16(Vg + nk, &LV[s2][t * 8]);
    }
    // ---- 36 independent MFMAs: PV[g-1] (carried, reg-only) then QK[g] ----
    __builtin_amdgcn_s_setprio(1);
#pragma unroll
    for (int dt = 0; dt < 4; dt++)
#pragma unroll
      for (int qt = 0; qt < 4; qt++)
        o[qt][dt] = __builtin_amdgcn_mfma_f32_16x16x32_f16(pfP[qt], vvP[dt], o[qt][dt], 0, 0, 0);
#pragma unroll
    for (int qt = 0; qt < 4; qt++)
      lacc[qt] = __builtin_amdgcn_mfma_f32_16x16x32_f16(pfP[qt], ones8, lacc[qt], 0, 0, 0);
    f32x4 sA[4], sB[4];
#pragma unroll
    for (int qt = 0; qt < 4; qt++) {
      sA[qt] = f32x4{0.f, 0.f, 0.f, 0.f};
      sA[qt] = __builtin_amdgcn_mfma_f32_16x16x32_f16(kk[0], qf[qt][0], sA[qt], 0, 0, 0);
      sA[qt] = __builtin_amdgcn_mfma_f32_16x16x32_f16(kk[1], qf[qt][1], sA[qt], 0, 0, 0);
      sB[qt] = f32x4{0.f, 0.f, 0.f, 0.f};
      sB[qt] = __builtin_amdgcn_mfma_f32_16x16x32_f16(kk[2], qf[qt][0], sB[qt], 0, 0, 0);
      sB[qt] = __builtin_amdgcn_mfma_f32_16x16x32_f16(kk[3], qf[qt][1], sB[qt], 0, 0, 0);
    }
    __builtin_amdgcn_s_setprio(0);
    // ---- exp[g] + pack -> carried state (in MFMA shadow) ----
#pragma unroll
    for (int qt = 0; qt < 4; qt++) {
      f16x2 a0 = pk_f16(fast_exp2(sA[qt][0]), fast_exp2(sA[qt][1]));
      f16x2 a1 = pk_f16(fast_exp2(sA[qt][2]), fast_exp2(sA[qt][3]));
      f16x2 b0 = pk_f16(fast_exp2(sB[qt][0]), fast_exp2(sB[qt][1]));
      f16x2 b1 = pk_f16(fast_exp2(sB[qt][2]), fast_exp2(sB[qt][3]));
      f16x4 lo = __builtin_shufflevector(a0, a1, 0, 1, 2, 3);
      f16x4 hi = __builtin_shufflevector(b0, b1, 0, 1, 2, 3);
      pfP[qt] = __builtin_shufflevector(lo, hi, 0, 1, 2, 3, 4, 5, 6, 7);
    }
#pragma unroll
    for (int i = 0; i < 4; i++) vvP[i] = vv[i];
    // counted barrier: this iter's 2 staging loads stay in flight
    asm volatile("s_waitcnt vmcnt(2)" ::: "memory");
    __builtin_amdgcn_s_barrier();
    cur = (cur == 2) ? 0 : cur + 1;
  }

  // ---- epilogue: PV[63] ----
#pragma unroll
  for (int dt = 0; dt < 4; dt++)
#pragma unroll
    for (int qt = 0; qt < 4; qt++)
      o[qt][dt] = __builtin_amdgcn_mfma_f32_16x16x32_f16(pfP[qt], vvP[dt], o[qt][dt], 0, 0, 0);
#pragma unroll
  for (int qt = 0; qt < 4; qt++)
    lacc[qt] = __builtin_amdgcn_mfma_f32_16x16x32_f16(pfP[qt], ones8, lacc[qt], 0, 0, 0);

  // lacc C-layout: lane holds q=quad*4+r (all cols equal) -> no shuffles
#pragma unroll
  for (int qt = 0; qt < 4; qt++) {
#pragma unroll
    for (int r = 0; r < 4; r++) {
      float inv = 1.0f / lacc[qt][r];
      int q = qb * 256 + wave * 64 + qt * 16 + quad * 4 + r;
#pragma unroll
      for (int dt = 0; dt < 4; dt++)
        out[((size_t)bb * NS + q) * ND + hh * 64 + dt * 16 + lr] = o[qt][dt][r] * inv;
    }
  }
}

extern "C" void kernel_launch(void* const* d_in, const int* in_sizes, int n_in,
                              void* d_out, int out_size, void* d_ws, size_t ws_size,
                              hipStream_t stream) {
  const float* X  = (const float*)d_in[0];
  const float* Wq = (const float*)d_in[1];
  const float* bq = (const float*)d_in[2];
  const float* Wk = (const float*)d_in[3];
  const float* bk = (const float*)d_in[4];
  const float* Wv = (const float*)d_in[5];
  const float* bv = (const float*)d_in[6];
  float* out = (float*)d_out;

  // ws: Xh 16MB | Wh 6MB | QF 16MB | KF 16MB | VF 16MB = 70MB
  f16* Xh = (f16*)d_ws;
  f16* Wh = (f16*)((char*)d_ws + (size_t)(16u << 20));
  f16* QF = (f16*)((char*)d_ws + (size_t)(22u << 20));
  f16* KF = (f16*)((char*)d_ws + (size_t)(38u << 20));
  f16* VF = (f16*)((char*)d_ws + (size_t)(54u << 20));

  cvt_all<<<11264, 256, 0, stream>>>(X, Wq, Wk, Wv, Xh, Wh);
  qkv_gemm<<<dim3(64, 24), 256, 0, stream>>>(Xh, Wh, bq, bk, bv, QF, KF, VF);
  attn_kernel<<<dim3(64, 8), 256, 0, stream>>>(QF, KF, VF, out);
}

// Round 10
// 215.219 us; speedup vs baseline: 1.3371x; 1.3371x over previous
//
#include <hip/hip_runtime.h>

typedef _Float16 f16;
typedef f16 f16x2 __attribute__((ext_vector_type(2)));
typedef f16 f16x4 __attribute__((ext_vector_type(4)));
typedef f16 f16x8 __attribute__((ext_vector_type(8)));
typedef float f32x4 __attribute__((ext_vector_type(4)));

#define NB 4
#define NS 2048
#define ND 1024
#define NH 16
#define NDH 64

__device__ __forceinline__ void gl2lds16(const void* g, void* l) {
  __builtin_amdgcn_global_load_lds(
      (const __attribute__((address_space(1))) unsigned int*)g,
      (__attribute__((address_space(3))) unsigned int*)l, 16, 0, 0);
}

__device__ __forceinline__ float fast_exp2(float x) {
  return __builtin_amdgcn_exp2f(x);  // v_exp_f32
}

__device__ __forceinline__ f16x2 pk_f16(float a, float b) {
  return __builtin_bit_cast(f16x2, __builtin_amdgcn_cvt_pkrtz(a, b));  // v_cvt_pkrtz_f16_f32
}

// ---------------- fp32 -> f16 conversion (all 4 inputs, one launch) ----------
__global__ __launch_bounds__(256) void cvt_all(
    const float* __restrict__ X, const float* __restrict__ Wq,
    const float* __restrict__ Wk, const float* __restrict__ Wv,
    f16* __restrict__ Xh, f16* __restrict__ Wh) {
  int b = blockIdx.x;
  const float* src;
  f16* dst;
  int off;
  if (b < 8192)       { src = X;  dst = Xh;               off = 0; }
  else if (b < 9216)  { src = Wq; dst = Wh;               off = 8192; }
  else if (b < 10240) { src = Wk; dst = Wh + (1u << 20);  off = 9216; }
  else                { src = Wv; dst = Wh + (2u << 20);  off = 10240; }
  int i = (b - off) * 256 + threadIdx.x;
  float4 v = ((const float4*)src)[i];
  f16x4 h = {(f16)v.x, (f16)v.y, (f16)v.z, (f16)v.w};
  ((f16x4*)dst)[i] = h;
}

// ---------------- fused QKV projection GEMM: T3 2-phase double-buffer -------
// R9 post-mortem: BK=32 ring = 151 µs (MfmaUtil 14) — 16 MFMA/barrier can't
// cover L2 latency at distance ~1 short iter.  Revert to BK=64 and apply the
// m97/T3-minimum pattern instead: double-buffered LDS (2x32 KB), issue next
// tile's 8 gl2lds BEFORE compute, vmcnt(0)+barrier AFTER the ~300 cyc of
// ds_read+MFMA — load latency hides under compute (old structure drained
// immediately after issue, exposing full latency every iter).
// Race audit: buf (k+1)&1 written during iter k was last read at iter k-1
// (barrier-ordered); its 8 loads drain at vmcnt(0) before barrier(k), one
// full compute phase after issue and before reads at k+1.
// Swizzle (R7-proven): phys chunk p of row r holds logical p^(r&7)
// (swizzled GLOBAL source, linear LDS dest); reads use ((c*4+quad)^(lr&7)).
// VF epilogue: i-pairs (0,1)/(2,3) share kt2 (ts=0/1) -> fused f16x8 store
// (16B/lane, full-line coverage; R9 showed WRITE_SIZE 3.2x ideal).
// QF/KF stored in K=32 MFMA fragment order (coalesced 16B/lane in attn):
//   frag f covers dh f*32..f*32+31 of a 16-row tile; lane L holds
//   M[row = tile*16 + (L&15)][dh = f*32 + (L>>4)*8 + j], j=0..7 (16B).
//   Address: (((bh*128+tile)*2+f)*64+L)*8 + j.   Q pre-scaled by 1/8*log2(e).
// VF stored in K=32 PV B-frag order over 32-key groups (kt2 = key>>5):
//   lane (quad,lr), slot j:  key = 32*kt2 + (j<4 ? quad*4+j : 16+quad*4+(j-4)),
//   dh = dt*16+lr.  addr = ((bh*64+kt2)*4+dt)*512 + lane*8 + j.
__global__ __launch_bounds__(256) void qkv_gemm(
    const f16* __restrict__ Xh, const f16* __restrict__ Wh,
    const float* __restrict__ bq, const float* __restrict__ bk,
    const float* __restrict__ bv,
    f16* __restrict__ QF, f16* __restrict__ KF, f16* __restrict__ VF) {
  __shared__ f16 Ah[2][128 * 64];
  __shared__ f16 Bh[2][128 * 64];
  const int t = threadIdx.x;
  const int tileM = blockIdx.x * 128;
  const int nGlob = blockIdx.y * 128;
  const int mat = nGlob >> 10;
  const int col0 = nGlob & 1023;
  const int wave = t >> 6, lane = t & 63;
  const int mOff = (wave & 1) * 64, nOff = (wave >> 1) * 64;
  const int lr = lane & 15, quad = lane >> 4;

  f32x4 acc[4][4];
#pragma unroll
  for (int i = 0; i < 4; i++)
#pragma unroll
    for (int j = 0; j < 4; j++) acc[i][j] = f32x4{0.f, 0.f, 0.f, 0.f};

  // staging: thread t owns phys (row = t>>3, chunk = t&7); source chunk is
  // swizzled so that phys chunk p of row r holds logical chunk p^(r&7).
  const int srow = t >> 3;                        // 0..31
  const int sx = ((t & 7) ^ (srow & 7)) * 8;      // f16 offset within row
  const f16* ag = Xh + (size_t)(tileM + srow) * ND + sx;
  const f16* bg = Wh + (size_t)mat * ND * ND + (size_t)(col0 + srow) * ND + sx;
  const bool qk = (mat < 2);
  const int rx = lr & 7;  // row&7 for all frag rows this lane reads

  // ---- prologue: stage k-iter 0 into buf 0; drain; barrier ----
  gl2lds16(ag,                       Ah[0] + t * 8);
  gl2lds16(ag + (size_t)32 * ND,     Ah[0] + 2048 + t * 8);
  gl2lds16(ag + (size_t)64 * ND,     Ah[0] + 4096 + t * 8);
  gl2lds16(ag + (size_t)96 * ND,     Ah[0] + 6144 + t * 8);
  gl2lds16(bg,                       Bh[0] + t * 8);
  gl2lds16(bg + (size_t)32 * ND,     Bh[0] + 2048 + t * 8);
  gl2lds16(bg + (size_t)64 * ND,     Bh[0] + 4096 + t * 8);
  gl2lds16(bg + (size_t)96 * ND,     Bh[0] + 6144 + t * 8);
  asm volatile("s_waitcnt vmcnt(0)" ::: "memory");
  __builtin_amdgcn_s_barrier();

  for (int kk = 0; kk < 16; ++kk) {
    const int buf = kk & 1;
    // issue next tile's staging BEFORE compute (latency hides under MFMA)
    if (kk < 15) {
      const size_t ko = (size_t)(kk + 1) * 64;
      gl2lds16(ag + ko,                       Ah[buf ^ 1] + t * 8);
      gl2lds16(ag + (size_t)32 * ND + ko,     Ah[buf ^ 1] + 2048 + t * 8);
      gl2lds16(ag + (size_t)64 * ND + ko,     Ah[buf ^ 1] + 4096 + t * 8);
      gl2lds16(ag + (size_t)96 * ND + ko,     Ah[buf ^ 1] + 6144 + t * 8);
      gl2lds16(bg + ko,                       Bh[buf ^ 1] + t * 8);
      gl2lds16(bg + (size_t)32 * ND + ko,     Bh[buf ^ 1] + 2048 + t * 8);
      gl2lds16(bg + (size_t)64 * ND + ko,     Bh[buf ^ 1] + 4096 + t * 8);
      gl2lds16(bg + (size_t)96 * ND + ko,     Bh[buf ^ 1] + 6144 + t * 8);
    }
    // compute current tile: 2 x (8 ds_read_b128 + 16 MFMA)
#pragma unroll
    for (int c = 0; c < 2; c++) {
      const int ch = ((c * 4 + quad) ^ rx) * 8;  // swizzled chunk (f16 units)
      f16x8 af[4], bf[4];
#pragma unroll
      for (int i = 0; i < 4; i++)
        af[i] = *(const f16x8*)(Ah[buf] + (mOff + i * 16 + lr) * 64 + ch);
#pragma unroll
      for (int j = 0; j < 4; j++)
        bf[j] = *(const f16x8*)(Bh[buf] + (nOff + j * 16 + lr) * 64 + ch);
      if (qk) {
#pragma unroll
        for (int i = 0; i < 4; i++)
#pragma unroll
          for (int j = 0; j < 4; j++)
            acc[i][j] = __builtin_amdgcn_mfma_f32_16x16x32_f16(bf[j], af[i], acc[i][j], 0, 0, 0);
      } else {
#pragma unroll
        for (int i = 0; i < 4; i++)
#pragma unroll
          for (int j = 0; j < 4; j++)
            acc[i][j] = __builtin_amdgcn_mfma_f32_16x16x32_f16(af[i], bf[j], acc[i][j], 0, 0, 0);
      }
    }
    // drain this iter's prefetch (issued ~300 cyc ago) + barrier
    asm volatile("s_waitcnt vmcnt(0)" ::: "memory");
    __builtin_amdgcn_s_barrier();
  }

  if (qk) {
    // acc[i][j][r] = C[dh_n = col0+nOff+j*16+quad*4+r][row = tileM+mOff+i*16+lr]
    const float* bias = (mat == 0) ? bq : bk;
    f16* dst = (mat == 0) ? QF : KF;
    const float sc = (mat == 0) ? 0.18033688f : 1.0f;  // 1/8*log2(e) folded into Q
    const int jstart = (quad & 1) * 4;
#pragma unroll
    for (int j = 0; j < 4; j++) {
      int n0 = col0 + nOff + j * 16;
      int h = n0 >> 6;
      int f = j >> 1;
      int lam = lr + 16 * ((2 * j + (quad >> 1)) & 3);
      float4 bb = *(const float4*)(bias + n0 + quad * 4);
#pragma unroll
      for (int i = 0; i < 4; i++) {
        int sF = tileM + mOff + i * 16;
        int b = sF >> 11, st = (sF & 2047) >> 4;
        int bh = b * NH + h;
        f16x4 v;
#pragma unroll
        for (int r = 0; r < 4; r++) v[r] = (f16)((acc[i][j][r] + (&bb.x)[r]) * sc);
        *(f16x4*)(dst + (((size_t)(bh * 128 + st) * 2 + f) * 64 + lam) * 8 + jstart) = v;
      }
    }
  } else {
    // acc[i][j][r] = C[key = tileM+mOff+i*16+quad*4+r][dh_n = col0+nOff+j*16+lr]
    // Fused full-line stores: i-pair (2p, 2p+1) shares kt2 with ts=0/1 ->
    // one f16x8 (16B/lane) store covers both k-slot halves.
#pragma unroll
    for (int j = 0; j < 4; j++) {
      int n = col0 + nOff + j * 16 + lr;
      int h = n >> 6, dt = (n >> 4) & 3;
      float bb = bv[n];
#pragma unroll
      for (int p = 0; p < 2; p++) {
        int i0 = 2 * p;
        int sF = tileM + mOff + i0 * 16;
        int b = sF >> 11;
        int kt2 = (sF & 2047) >> 5;
        int bh = b * NH + h;
        f16x8 v;
#pragma unroll
        for (int r = 0; r < 4; r++) {
          v[r] = (f16)(acc[i0][j][r] + bb);
          v[4 + r] = (f16)(acc[i0 + 1][j][r] + bb);
        }
        *(f16x8*)(VF + ((size_t)(bh * 64 + kt2) * 4 + dt) * 512 +
                  (size_t)(quad * 16 + lr) * 8) = v;
      }
    }
  }
}

// ------- flash attention: LDS K/V ring + counted-vmcnt barriers (T4+T5) -----
// (unchanged from R7 — 66 µs, MfmaUtil 51)
__global__ __launch_bounds__(256, 2) void attn_kernel(
    const f16* __restrict__ QF, const f16* __restrict__ KF,
    const f16* __restrict__ VF, float* __restrict__ out) {
  __shared__ f16 LK[3][2048];
  __shared__ f16 LV[3][2048];
  const int t = threadIdx.x, wave = t >> 6, lane = t & 63;
  const int lr = lane & 15, quad = lane >> 4;
  const int bh = blockIdx.x, qb = blockIdx.y;
  const int bb = bh >> 4, hh = bh & 15;
  const size_t bhOff = (size_t)bh * 131072;  // 256 KB of f16 per bh
  const f16* Qp = QF + bhOff + (size_t)lane * 8;
  const f16* Kg = KF + bhOff + (size_t)t * 8;  // staging: thread t -> 16B
  const f16* Vg = VF + bhOff + (size_t)t * 8;
  const int st0 = qb * 16 + wave * 4;  // first of 4 q-tiles for this wave

  // Q B-frags for K=32 (n=q=lane&15, k=dh=(lane>>4)*8+j + f*32), pre-scaled
  f16x8 qf[4][2];
#pragma unroll
  for (int qt = 0; qt < 4; qt++) {
    qf[qt][0] = *(const f16x8*)(Qp + (size_t)(st0 + qt) * 1024);
    qf[qt][1] = *(const f16x8*)(Qp + (size_t)(st0 + qt) * 1024 + 512);
  }

  f32x4 o[4][4];
#pragma unroll
  for (int qt = 0; qt < 4; qt++)
#pragma unroll
    for (int dt = 0; dt < 4; dt++) o[qt][dt] = f32x4{0.f, 0.f, 0.f, 0.f};
  f32x4 lacc[4];
#pragma unroll
  for (int qt = 0; qt < 4; qt++) lacc[qt] = f32x4{0.f, 0.f, 0.f, 0.f};
  const f16x8 ones8 = {(f16)1.f, (f16)1.f, (f16)1.f, (f16)1.f,
                       (f16)1.f, (f16)1.f, (f16)1.f, (f16)1.f};

  // carried pipeline state: P and V of the previous group
  f16x8 pfP[4], vvP[4];

  // ---- prologue: stage groups 0,1; wait group 0 only (vmcnt(2)) ----
  gl2lds16(Kg,        &LK[0][t * 8]);
  gl2lds16(Vg,        &LV[0][t * 8]);
  gl2lds16(Kg + 2048, &LK[1][t * 8]);
  gl2lds16(Vg + 2048, &LV[1][t * 8]);
  asm volatile("s_waitcnt vmcnt(2)" ::: "memory");
  __builtin_amdgcn_s_barrier();

  // ---- peeled g = 0: QK[0] + exp[0]; stage group 2 ----
  {
    f16x8 kk[4];
#pragma unroll
    for (int i = 0; i < 4; i++)
      kk[i] = *(const f16x8*)(&LK[0][i * 512 + lane * 8]);
#pragma unroll
    for (int i = 0; i < 4; i++)
      vvP[i] = *(const f16x8*)(&LV[0][i * 512 + lane * 8]);
    gl2lds16(Kg + 2 * 2048, &LK[2][t * 8]);
    gl2lds16(Vg + 2 * 2048, &LV[2][t * 8]);
    f32x4 sA[4], sB[4];
#pragma unroll
    for (int qt = 0; qt < 4; qt++) {
      sA[qt] = f32x4{0.f, 0.f, 0.f, 0.f};
      sA[qt] = __builtin_amdgcn_mfma_f32_16x16x32_f16(kk[0], qf[qt][0], sA[qt], 0, 0, 0);
      sA[qt] = __builtin_amdgcn_mfma_f32_16x16x32_f16(kk[1], qf[qt][1], sA[qt], 0, 0, 0);
      sB[qt] = f32x4{0.f, 0.f, 0.f, 0.f};
      sB[qt] = __builtin_amdgcn_mfma_f32_16x16x32_f16(kk[2], qf[qt][0], sB[qt], 0, 0, 0);
      sB[qt] = __builtin_amdgcn_mfma_f32_16x16x32_f16(kk[3], qf[qt][1], sB[qt], 0, 0, 0);
    }
#pragma unroll
    for (int qt = 0; qt < 4; qt++) {
      f16x2 a0 = pk_f16(fast_exp2(sA[qt][0]), fast_exp2(sA[qt][1]));
      f16x2 a1 = pk_f16(fast_exp2(sA[qt][2]), fast_exp2(sA[qt][3]));
      f16x2 b0 = pk_f16(fast_exp2(sB[qt][0]), fast_exp2(sB[qt][1]));
      f16x2 b1 = pk_f16(fast_exp2(sB[qt][2]), fast_exp2(sB[qt][3]));
      f16x4 lo = __builtin_shufflevector(a0, a1, 0, 1, 2, 3);
      f16x4 hi = __builtin_shufflevector(b0, b1, 0, 1, 2, 3);
      pfP[qt] = __builtin_shufflevector(lo, hi, 0, 1, 2, 3, 4, 5, 6, 7);
    }
  }
  asm volatile("s_waitcnt vmcnt(2)" ::: "memory");  // group-1 loads landed
  __builtin_amdgcn_s_barrier();

  int cur = 1;  // g % 3
  for (int g = 1; g < 64; ++g) {
    // read group g fragments (linear 16B/lane, conflict-free)
    f16x8 kk[4], vv[4];
#pragma unroll
    for (int i = 0; i < 4; i++)
      kk[i] = *(const f16x8*)(&LK[cur][i * 512 + lane * 8]);
#pragma unroll
    for (int i = 0; i < 4; i++)
      vv[i] = *(const f16x8*)(&LV[cur][i * 512 + lane * 8]);
    // stage group (g+2)&63 into buf (g+2)%3 (wrap staging: harmless, no branch)
    {
      int s2 = cur + 2; if (s2 >= 3) s2 -= 3;
      const size_t nk = (size_t)((g + 2) & 63) * 2048;
      gl2lds16(Kg + nk, &LK[s2][t * 8]);
      gl2lds16(Vg + nk, &LV[s2][t * 8]);
    }
    // ---- 36 independent MFMAs: PV[g-1] (carried, reg-only) then QK[g] ----
    __builtin_amdgcn_s_setprio(1);
#pragma unroll
    for (int dt = 0; dt < 4; dt++)
#pragma unroll
      for (int qt = 0; qt < 4; qt++)
        o[qt][dt] = __builtin_amdgcn_mfma_f32_16x16x32_f16(pfP[qt], vvP[dt], o[qt][dt], 0, 0, 0);
#pragma unroll
    for (int qt = 0; qt < 4; qt++)
      lacc[qt] = __builtin_amdgcn_mfma_f32_16x16x32_f16(pfP[qt], ones8, lacc[qt], 0, 0, 0);
    f32x4 sA[4], sB[4];
#pragma unroll
    for (int qt = 0; qt < 4; qt++) {
      sA[qt] = f32x4{0.f, 0.f, 0.f, 0.f};
      sA[qt] = __builtin_amdgcn_mfma_f32_16x16x32_f16(kk[0], qf[qt][0], sA[qt], 0, 0, 0);
      sA[qt] = __builtin_amdgcn_mfma_f32_16x16x32_f16(kk[1], qf[qt][1], sA[qt], 0, 0, 0);
      sB[qt] = f32x4{0.f, 0.f, 0.f, 0.f};
      sB[qt] = __builtin_amdgcn_mfma_f32_16x16x32_f16(kk[2], qf[qt][0], sB[qt], 0, 0, 0);
      sB[qt] = __builtin_amdgcn_mfma_f32_16x16x32_f16(kk[3], qf[qt][1], sB[qt], 0, 0, 0);
    }
    __builtin_amdgcn_s_setprio(0);
    // ---- exp[g] + pack -> carried state (in MFMA shadow) ----
#pragma unroll
    for (int qt = 0; qt < 4; qt++) {
      f16x2 a0 = pk_f16(fast_exp2(sA[qt][0]), fast_exp2(sA[qt][1]));
      f16x2 a1 = pk_f16(fast_exp2(sA[qt][2]), fast_exp2(sA[qt][3]));
      f16x2 b0 = pk_f16(fast_exp2(sB[qt][0]), fast_exp2(sB[qt][1]));
      f16x2 b1 = pk_f16(fast_exp2(sB[qt][2]), fast_exp2(sB[qt][3]));
      f16x4 lo = __builtin_shufflevector(a0, a1, 0, 1, 2, 3);
      f16x4 hi = __builtin_shufflevector(b0, b1, 0, 1, 2, 3);
      pfP[qt] = __builtin_shufflevector(lo, hi, 0, 1, 2, 3, 4, 5, 6, 7);
    }
#pragma unroll
    for (int i = 0; i < 4; i++) vvP[i] = vv[i];
    // counted barrier: this iter's 2 staging loads stay in flight
    asm volatile("s_waitcnt vmcnt(2)" ::: "memory");
    __builtin_amdgcn_s_barrier();
    cur = (cur == 2) ? 0 : cur + 1;
  }

  // ---- epilogue: PV[63] ----
#pragma unroll
  for (int dt = 0; dt < 4; dt++)
#pragma unroll
    for (int qt = 0; qt < 4; qt++)
      o[qt][dt] = __builtin_amdgcn_mfma_f32_16x16x32_f16(pfP[qt], vvP[dt], o[qt][dt], 0, 0, 0);
#pragma unroll
  for (int qt = 0; qt < 4; qt++)
    lacc[qt] = __builtin_amdgcn_mfma_f32_16x16x32_f16(pfP[qt], ones8, lacc[qt], 0, 0, 0);

  // lacc C-layout: lane holds q=quad*4+r (all cols equal) -> no shuffles
#pragma unroll
  for (int qt = 0; qt < 4; qt++) {
#pragma unroll
    for (int r = 0; r < 4; r++) {
      float inv = 1.0f / lacc[qt][r];
      int q = qb * 256 + wave * 64 + qt * 16 + quad * 4 + r;
#pragma unroll
      for (int dt = 0; dt < 4; dt++)
        out[((size_t)bb * NS + q) * ND + hh * 64 + dt * 16 + lr] = o[qt][dt][r] * inv;
    }
  }
}

extern "C" void kernel_launch(void* const* d_in, const int* in_sizes, int n_in,
                              void* d_out, int out_size, void* d_ws, size_t ws_size,
                              hipStream_t stream) {
  const float* X  = (const float*)d_in[0];
  const float* Wq = (const float*)d_in[1];
  const float* bq = (const float*)d_in[2];
  const float* Wk = (const float*)d_in[3];
  const float* bk = (const float*)d_in[4];
  const float* Wv = (const float*)d_in[5];
  const float* bv = (const float*)d_in[6];
  float* out = (float*)d_out;

  // ws: Xh 16MB | Wh 6MB | QF 16MB | KF 16MB | VF 16MB = 70MB
  f16* Xh = (f16*)d_ws;
  f16* Wh = (f16*)((char*)d_ws + (size_t)(16u << 20));
  f16* QF = (f16*)((char*)d_ws + (size_t)(22u << 20));
  f16* KF = (f16*)((char*)d_ws + (size_t)(38u << 20));
  f16* VF = (f16*)((char*)d_ws + (size_t)(54u << 20));

  cvt_all<<<11264, 256, 0, stream>>>(X, Wq, Wk, Wv, Xh, Wh);
  qkv_gemm<<<dim3(64, 24), 256, 0, stream>>>(Xh, Wh, bq, bk, bv, QF, KF, VF);
  attn_kernel<<<dim3(64, 8), 256, 0, stream>>>(QF, KF, VF, out);
}